// Round 1
// baseline (121.845 us; speedup 1.0000x reference)
//
#include <hip/hip_runtime.h>

// out[b][t][w] (float4) = x[b][(t + w - 15) mod T] (float4)
// B=128, T=16384, F=4, wow=16  ->  total float4 elements = 2^25.

__global__ __launch_bounds__(256) void ring_pad_kernel(
    const float4* __restrict__ x, float4* __restrict__ out, int total) {
    constexpr int WOW = 16;
    constexpr int T   = 16384;
    constexpr int SHIFT = T - WOW + 1;  // +T so (t + w - 15) stays non-negative

    int stride = gridDim.x * blockDim.x;
    for (int i = blockIdx.x * blockDim.x + threadIdx.x; i < total; i += stride) {
        int w = i & (WOW - 1);          // window slot 0..15
        int t = (i >> 4) & (T - 1);     // time index
        int b = i >> 18;                // batch (i >> (4 + 14))
        int src = (t + w + SHIFT) & (T - 1);
        out[i] = x[b * T + src];
    }
}

extern "C" void kernel_launch(void* const* d_in, const int* in_sizes, int n_in,
                              void* d_out, int out_size, void* d_ws, size_t ws_size,
                              hipStream_t stream) {
    const float4* x = (const float4*)d_in[0];   // (128, 16384, 4) fp32 -> float4 rows
    float4* out = (float4*)d_out;               // (128, 16384, 64) fp32 -> float4 per (b,t,w)

    int total = out_size / 4;                    // number of float4 stores = 2^25
    int threads = 256;
    int blocks = 8192;                           // grid-stride: 16 iters/thread, full-GPU
    ring_pad_kernel<<<blocks, threads, 0, stream>>>(x, out, total);
}

// Round 3
// 118.721 us; speedup vs baseline: 1.0263x; 1.0263x over previous
//
#include <hip/hip_runtime.h>

// out[b][t][w] (f32x4) = x[b][(t + w - 15) mod T] (f32x4)
// B=128, T=16384, F=4, wow=16  ->  total f32x4 elements = 2^25.
//
// Memory-bound: 537 MB NT stores + ~34 MB cached reads (x is L2/L3-resident,
// re-read 16x). NT stores keep the output stream from thrashing L2/L3.

typedef float f32x4 __attribute__((ext_vector_type(4)));

__global__ __launch_bounds__(256) void ring_pad_kernel(
    const f32x4* __restrict__ x, f32x4* __restrict__ out, int total) {
    constexpr int WOW = 16;
    constexpr int T   = 16384;
    constexpr int SHIFT = T - WOW + 1;  // +T so (t + w - 15) stays non-negative

    int stride = gridDim.x * blockDim.x;
    int half = total >> 1;
    // 2-way ILP: each thread services index i and i+half (independent streams).
    for (int i = blockIdx.x * blockDim.x + threadIdx.x; i < half; i += stride) {
        int j = i + half;

        int w0 = i & (WOW - 1);
        int t0 = (i >> 4) & (T - 1);
        int b0 = i >> 18;
        int s0 = (t0 + w0 + SHIFT) & (T - 1);

        int w1 = j & (WOW - 1);
        int t1 = (j >> 4) & (T - 1);
        int b1 = j >> 18;
        int s1 = (t1 + w1 + SHIFT) & (T - 1);

        f32x4 v0 = x[b0 * T + s0];
        f32x4 v1 = x[b1 * T + s1];
        __builtin_nontemporal_store(v0, &out[i]);
        __builtin_nontemporal_store(v1, &out[j]);
    }
}

extern "C" void kernel_launch(void* const* d_in, const int* in_sizes, int n_in,
                              void* d_out, int out_size, void* d_ws, size_t ws_size,
                              hipStream_t stream) {
    const f32x4* x = (const f32x4*)d_in[0];   // (128, 16384, 4) fp32 -> f32x4 rows
    f32x4* out = (f32x4*)d_out;               // (128, 16384, 64) fp32 -> f32x4 per (b,t,w)

    int total = out_size / 4;                  // number of f32x4 stores = 2^25
    int threads = 256;
    int blocks = 8192;                         // grid-stride over half-range (2 f4/thread/iter)
    ring_pad_kernel<<<blocks, threads, 0, stream>>>(x, out, total);
}

// Round 4
// 112.292 us; speedup vs baseline: 1.0851x; 1.0572x over previous
//
#include <hip/hip_runtime.h>

// out[b][t][w] (f32x4) = x[b][(t + w - 15) mod T] (f32x4)
// B=128, T=16384, F=4, wow=16.
//
// Store-issue-limited: 537 MB of NT stores. Reads are deduped through LDS
// (4.3 KB staged per block) so the VMEM pipe is ~pure stores, matching the
// pure-fill issue mix (~6.7 TB/s measured on this chip).

typedef float f32x4 __attribute__((ext_vector_type(4)));

__global__ __launch_bounds__(256) void ring_pad_kernel(
    const f32x4* __restrict__ x, f32x4* __restrict__ out) {
    constexpr int T     = 16384;
    constexpr int WOW   = 16;
    constexpr int LROWS = 256 + WOW - 1;  // 271 staged rows

    __shared__ f32x4 lx[LROWS];

    int b  = blockIdx.x >> 6;            // blockIdx / 64   (batch)
    int t0 = (blockIdx.x & 63) << 8;     // (blockIdx % 64) * 256
    int k  = threadIdx.x;

    // Stage x rows t0-15 .. t0+255 (mod T): coalesced 16B/lane loads.
    const f32x4* xb = x + (size_t)b * T;
    lx[k] = xb[(t0 - (WOW - 1) + k) & (T - 1)];
    if (k < LROWS - 256)
        lx[k + 256] = xb[(t0 - (WOW - 1) + k + 256) & (T - 1)];
    __syncthreads();

    // Output tile: 256 rows x 64 floats = 64 KB, fully coalesced NT stores.
    // Thread k covers window slot w = k&15 of local rows tl, tl+16, ...
    int w  = k & (WOW - 1);
    int tl = k >> 4;                     // 0..15
    f32x4* ob = out + ((size_t)(b * T + t0) << 4);

    #pragma unroll
    for (int it = 0; it < 16; ++it) {
        // local src row = (t - t0) + w  where t - t0 = it*16 + tl
        f32x4 v = lx[it * 16 + tl + w];
        __builtin_nontemporal_store(v, &ob[it * 256 + k]);
    }
}

extern "C" void kernel_launch(void* const* d_in, const int* in_sizes, int n_in,
                              void* d_out, int out_size, void* d_ws, size_t ws_size,
                              hipStream_t stream) {
    const f32x4* x = (const f32x4*)d_in[0];   // (128, 16384, 4) fp32
    f32x4* out = (f32x4*)d_out;               // (128, 16384, 64) fp32

    int blocks = 128 * 64;                     // one block per (b, 256-row tile)
    ring_pad_kernel<<<blocks, 256, 0, stream>>>(x, out);
}

// Round 5
// 100.993 us; speedup vs baseline: 1.2065x; 1.1119x over previous
//
#include <hip/hip_runtime.h>

// out[b][t][w] (f32x4) = x[b][(t + w - 15) mod T] (f32x4)
// B=128, T=16384, F=4, wow=16.
//
// Persistent sweep kernel: 2048 blocks (8/CU resident), 16 iterations.
// Each iteration the WHOLE device writes one contiguous 32 MB span of out
// (fill-kernel-like DRAM row locality), with x rows deduped through
// double-buffered LDS and a depth-1 register prefetch.

typedef float f32x4 __attribute__((ext_vector_type(4)));

__global__ __launch_bounds__(256) void ring_pad_kernel(
    const f32x4* __restrict__ x, f32x4* __restrict__ out) {
    constexpr int T     = 16384;
    constexpr int WOW   = 16;
    constexpr int ROWS  = 64;               // t-rows per block per iteration
    constexpr int LROWS = ROWS + WOW - 1;   // 79 staged rows (1.26 KB)
    constexpr int ITER  = 16;

    __shared__ f32x4 lx[2][LROWS];

    int blk = blockIdx.x;                   // 0..2047
    int tid = threadIdx.x;                  // 0..255
    int t0    = (blk & 255) * ROWS;         // fixed t-tile per block
    int bslab = blk >> 8;                   // 0..7; b = m*8 + bslab

    int w  = tid & 15;                      // window slot
    int tl = tid >> 4;                      // 0..15 row-within-sub-stripe

    int  srow   = (t0 - (WOW - 1) + tid) & (T - 1);
    bool stager = tid < LROWS;

    // Prefetch iteration 0's rows into registers.
    f32x4 r;
    if (stager) r = x[((size_t)bslab << 14) + srow];

    for (int m = 0; m < ITER; ++m) {
        f32x4* buf = lx[m & 1];
        if (stager) buf[tid] = r;
        // Prefetch next iteration (b advances by 8); clamp keeps last-iter
        // load in-bounds (value unused).
        int bn = (m * 8 + 8 + bslab) & 127;
        if (stager) r = x[((size_t)bn << 14) + srow];
        __syncthreads();   // stage visible; prev-buffer reads (m-2) long done

        int b = m * 8 + bslab;
        f32x4* ob = out + ((((size_t)b << 14) + (size_t)t0) << 4);
        #pragma unroll
        for (int s = 0; s < 4; ++s) {
            // out idx in block = s*256 + tid -> t_local = s*16 + tl, slot w
            f32x4 v = buf[s * 16 + tl + w];
            __builtin_nontemporal_store(v, &ob[s * 256 + tid]);
        }
    }
}

extern "C" void kernel_launch(void* const* d_in, const int* in_sizes, int n_in,
                              void* d_out, int out_size, void* d_ws, size_t ws_size,
                              hipStream_t stream) {
    const f32x4* x = (const f32x4*)d_in[0];   // (128, 16384, 4) fp32
    f32x4* out = (f32x4*)d_out;               // (128, 16384, 64) fp32

    ring_pad_kernel<<<2048, 256, 0, stream>>>(x, out);
}